// Round 4
// baseline (326.295 us; speedup 1.0000x reference)
//
#include <hip/hip_runtime.h>

// Problem constants
#define NB 4
#define NA 3
#define NS 1024
#define NHID 768
#define NHEADS 12
#define HD 64

typedef __bf16 bf16_t;
typedef __bf16 bf16x8 __attribute__((ext_vector_type(8)));
typedef __bf16 bf16x4 __attribute__((ext_vector_type(4)));
typedef float f32x4 __attribute__((ext_vector_type(4)));

#define MFMA(a, b, c) __builtin_amdgcn_mfma_f32_16x16x32_bf16(a, b, c, 0, 0, 0)

static __device__ __forceinline__ bf16x8 load8(const bf16_t* p) {
    return *reinterpret_cast<const bf16x8*>(p);
}

// async global->LDS, 16B per lane. LDS dest = wave-uniform base + lane*16.
typedef __attribute__((address_space(3))) unsigned int u32_lds;
typedef __attribute__((address_space(1))) unsigned int u32_glb;
static __device__ __forceinline__ void gl_lds16(const void* g, void* lds_base_uniform) {
    __builtin_amdgcn_global_load_lds((const u32_glb*)g, (u32_lds*)lds_base_uniform, 16, 0, 0);
}

static __device__ __forceinline__ bf16x8 cvt8(f32x4 lo, f32x4 hi) {
    bf16x8 r;
    r[0] = (bf16_t)lo[0]; r[1] = (bf16_t)lo[1]; r[2] = (bf16_t)lo[2]; r[3] = (bf16_t)lo[3];
    r[4] = (bf16_t)hi[0]; r[5] = (bf16_t)hi[1]; r[6] = (bf16_t)hi[2]; r[7] = (bf16_t)hi[3];
    return r;
}

// ---------------------------------------------------------------------------
// Vp layout (R14): per (bh,a): 32 sb-blocks (s in chunks of 32) of 4KB:
//   byte = (bh*NA+a)*131072 + sb*4096 + dt*1024 + (q*16 + l)*16 + e*2
// holding V[d = dt*16+l][s = sb*32 + s5] with s5 = (e>>2)*16 + q*4 + (e&3).
// This makes attn's VT staging a contiguous 1KB read per (a,dt) instr, and
// matches the swapped-QK P fragment k-order (k-slot q*8+e <-> s5) exactly.
// ---------------------------------------------------------------------------

// ---------------------------------------------------------------------------
// fp32 -> bf16 bulk conversion, up to 6 segments. Each block handles 4096
// elems (256 thr x 4 x f32x4). cN are CUMULATIVE block boundaries.
// ---------------------------------------------------------------------------
__global__ __launch_bounds__(256) void cvt6(
    const float* __restrict__ s0, bf16_t* __restrict__ d0, int c0,
    const float* __restrict__ s1, bf16_t* __restrict__ d1, int c1,
    const float* __restrict__ s2, bf16_t* __restrict__ d2, int c2,
    const float* __restrict__ s3, bf16_t* __restrict__ d3, int c3,
    const float* __restrict__ s4, bf16_t* __restrict__ d4, int c4,
    const float* __restrict__ s5, bf16_t* __restrict__ d5, int c5)
{
    const int bid = blockIdx.x;
    const float* s; bf16_t* d; int rel;
    if      (bid < c0) { s = s0; d = d0; rel = bid; }
    else if (bid < c1) { s = s1; d = d1; rel = bid - c0; }
    else if (bid < c2) { s = s2; d = d2; rel = bid - c1; }
    else if (bid < c3) { s = s3; d = d3; rel = bid - c2; }
    else if (bid < c4) { s = s4; d = d4; rel = bid - c3; }
    else               { s = s5; d = d5; rel = bid - c4; }
    const int t = threadIdx.x;
#pragma unroll
    for (int k = 0; k < 4; k++) {
        size_t u = (size_t)rel * 1024 + k * 256 + t;   // f32x4 unit index
        f32x4 v = reinterpret_cast<const f32x4*>(s)[u];
        bf16x4 o;
        o[0] = (bf16_t)v[0]; o[1] = (bf16_t)v[1];
        o[2] = (bf16_t)v[2]; o[3] = (bf16_t)v[3];
        reinterpret_cast<bf16x4*>(d)[u] = o;
    }
}

// ---------------------------------------------------------------------------
// R14: barrier-free wave-private GEMM. Block = 1 wave (64 thr) owning a
// 64x64 tile; 16KB private LDS (2 bufs x [A 4K | B 4K]) => 10 blocks/CU of
// fully independent waves. Per iter: vmcnt(8) [own stage(it) done, stage
// (it+1) in flight] -> 8 ds_read_b128 -> lgkmcnt(0) -> issue stage(it+2)
// into the buffer just read -> 16 MFMA. ZERO s_barrier in the kernel; the
// only ordering is the wave's own counters. Staged traffic is 2x the
// cooperative 128^2 tile but lands at ~26us of L2 BW -- far below the
// lockstep-barrier latency it replaces (R13: MfmaUtil 13%, nothing
// saturated, 7x above MFMA floor).
// WMODE 1: KV (n<768 -> K scalar stores; n>=768 -> Vp LDS-transpose
//          epilogue, fully-coalesced 16B/lane stores)
// WMODE 4: merged QKV: blocks [0,4608) KV; [4608,5376) Q via X2/W2/bias2.
// WMODE 3: O-proj: fp32 out + resid.
// ---------------------------------------------------------------------------
template <int WMODE, int NT>
__global__ __launch_bounds__(64) void wgemm(
    const bf16_t* __restrict__ X,
    const bf16_t* __restrict__ W0, const bf16_t* __restrict__ W1,
    const float* __restrict__ bias0, const float* __restrict__ bias1,
    const float* __restrict__ resid,
    bf16_t* __restrict__ out0, bf16_t* __restrict__ outV,
    float* __restrict__ outf,
    const bf16_t* __restrict__ X2, const bf16_t* __restrict__ W2,
    const float* __restrict__ bias2, bf16_t* __restrict__ out2)
{
    __shared__ __align__(16) char smem[2][8192];   // [buf][A 4K | B 4K]

    const int lane = threadIdx.x & 63;
    const int quad = lane >> 4, l15 = lane & 15;

    int emode = (WMODE == 4) ? 1 : WMODE;
    int nt    = NT;
    int bid   = blockIdx.x;
    const bf16_t* Xp = X;
    const bf16_t* Wp = W0;
    const float*  b0 = bias0;
    bf16_t*       o0 = out0;
    if constexpr (WMODE == 4) {
        if (bid >= 4608) {
            emode = 0; nt = 12; bid -= 4608;
            Xp = X2; Wp = W2; b0 = bias2; o0 = out2;
        }
    }
    const int xcd = bid & 7, jj = bid >> 3;
    const int n_t = jj % nt, slab = jj / nt;
    const int m0 = (slab * 8 + xcd) * 64;
    const int n0 = n_t * 64;

    const bf16_t* Wsel = (emode == 1 && n0 >= 768) ? W1 : Wp;
    const int n0b = (emode == 1 && n0 >= 768) ? n0 - 768 : n0;

    const bf16_t* Ap[4];
    const bf16_t* Bp[4];
#pragma unroll
    for (int i = 0; i < 4; i++) {
        Ap[i] = Xp   + (size_t)(m0  + i * 16 + l15) * NHID + quad * 8;
        Bp[i] = Wsel + (size_t)(n0b + i * 16 + l15) * NHID + quad * 8;
    }
    auto stage = [&](char* base) {
#pragma unroll
        for (int i = 0; i < 4; i++) { gl_lds16(Ap[i], base + i * 1024);        Ap[i] += 32; }
#pragma unroll
        for (int i = 0; i < 4; i++) { gl_lds16(Bp[i], base + 4096 + i * 1024); Bp[i] += 32; }
    };

    f32x4 acc[4][4];
#pragma unroll
    for (int i = 0; i < 4; i++)
#pragma unroll
        for (int j = 0; j < 4; j++) acc[i][j] = 0.0f;

    constexpr int KITER = NHID / 32;   // 24
    stage(smem[0]);
    stage(smem[1]);

    for (int it = 0; it < KITER; ++it) {
        if (it == KITER - 1) asm volatile("s_waitcnt vmcnt(0)" ::: "memory");
        else                 asm volatile("s_waitcnt vmcnt(8)" ::: "memory");
        char* cur = smem[it & 1];
        bf16x8 af[4], bfr[4];
#pragma unroll
        for (int i = 0; i < 4; i++) af[i]  = *(const bf16x8*)(cur + (i * 64 + lane) * 16);
#pragma unroll
        for (int j = 0; j < 4; j++) bfr[j] = *(const bf16x8*)(cur + 4096 + (j * 64 + lane) * 16);
        // own ds_reads retired before the DMA can overwrite this buffer
        asm volatile("s_waitcnt lgkmcnt(0)" ::: "memory");
        if (it + 2 < KITER) stage(cur);
#pragma unroll
        for (int i = 0; i < 4; i++)
#pragma unroll
            for (int j = 0; j < 4; j++)
                acc[i][j] = MFMA(af[i], bfr[j], acc[i][j]);
    }

    // ---- epilogue ----
    if (emode == 1 && n0 >= 768) {
        // Vp LDS-transpose: build 8KB image (2 sb chunks x 4KB) then flat
        // coalesced copy. hh fixed per wave (n0 64-aligned); d = j*16+l15.
        char* img = smem[0];
        const int hh  = (n0 - 768) >> 6;
        const int b   = m0 / (NA * NS);
        const int rem = m0 - b * (NA * NS);
        const int a   = rem >> 10;
        const int s0  = rem & 1023;
#pragma unroll
        for (int i = 0; i < 4; i++) {
#pragma unroll
            for (int j = 0; j < 4; j++) {
                float bn = bias1[(n0 - 768) + j * 16 + l15];
                bf16x4 pk;
#pragma unroll
                for (int rg = 0; rg < 4; rg++) pk[rg] = (bf16_t)(acc[i][j][rg] + bn);
                int off = (i >> 1) * 4096 + j * 1024 + (quad * 16 + l15) * 16 + (i & 1) * 8;
                *reinterpret_cast<bf16x4*>(img + off) = pk;
            }
        }
        asm volatile("s_waitcnt lgkmcnt(0)" ::: "memory");
        char* gbase = (char*)outV + (size_t)((b * NHEADS + hh) * NA + a) * 131072
                      + (size_t)(s0 >> 5) * 4096;
#pragma unroll
        for (int p = 0; p < 8; p++) {
            f32x4 v = *reinterpret_cast<const f32x4*>(img + p * 1024 + lane * 16);
            *reinterpret_cast<f32x4*>(gbase + p * 1024 + lane * 16) = v;
        }
    } else {
#pragma unroll
        for (int i = 0; i < 4; i++) {
#pragma unroll
            for (int j = 0; j < 4; j++) {
                const int n = n0 + j * 16 + l15;
                const float bn = b0[n];
#pragma unroll
                for (int rg = 0; rg < 4; rg++) {
                    const int m = m0 + i * 16 + quad * 4 + rg;
                    float v = acc[i][j][rg] + bn;
                    if (emode == 0) {
                        int b = m >> 10, s = m & 1023, hh = n >> 6, d = n & 63;
                        o0[(((size_t)(b * NHEADS + hh) * NS) + s) * HD + d] = (bf16_t)v;
                    } else if (emode == 1) {
                        int b = m / (NA * NS);
                        int rem = m - b * (NA * NS);
                        int a = rem >> 10, s = rem & 1023;
                        int hh = n >> 6, d = n & 63;
                        o0[((((size_t)(b * NHEADS + hh) * NA + a) * NS) + s) * HD + d] = (bf16_t)v;
                    } else {
                        v += resid[(size_t)m * NHID + n];
                        outf[(size_t)m * NHID + n] = v;
                    }
                }
            }
        }
    }
}

// ---------------------------------------------------------------------------
// Fallback-tier projection GEMM (R13 structure, kept for tiers 2/3).
// 128x128 tile, BK=32, 4 waves, counted-vmcnt depth-2, triple-buffered.
// R14: VT epilogue now writes the Vp layout (bf16x4-packed scalar stores).
// ---------------------------------------------------------------------------
template <int MODE, int NT, bool ABF, bool BBF>
__global__ __launch_bounds__(256) void proj_gemm(
    const void* __restrict__ Xv,
    const void* __restrict__ W0v, const void* __restrict__ W1v,
    const float* __restrict__ bias0, const float* __restrict__ bias1,
    const float* __restrict__ resid,
    bf16_t* __restrict__ out0, bf16_t* __restrict__ out1,
    float* __restrict__ outf)
{
    constexpr int ASZ   = ABF ? 8192 : 16384;
    constexpr int BSZ   = BBF ? 8192 : 16384;
    constexpr int BUFSZ = ASZ + BSZ;
    constexpr int LPS   = (ABF ? 2 : 4) + (BBF ? 2 : 4);
    __shared__ __align__(16) char smem[3 * BUFSZ];

    const int t = threadIdx.x;
    const int lane = t & 63, w = t >> 6;
    const int quad = lane >> 4, l15 = lane & 15;
    const int wm = w >> 1, wn = w & 1;

    const int bid = blockIdx.x;
    const int xcd = bid & 7, jj = bid >> 3;
    const int n_t = jj % NT, slab = jj / NT;
    const int m0 = (slab * 8 + xcd) * 128;
    const int n0 = n_t * 128;

    const void* Wselv = (MODE == 1 && n0 >= 768) ? W1v : W0v;
    const int n0b = (MODE == 1 && n0 >= 768) ? n0 - 768 : n0;

    const int srow  = lane >> 3;
    const int schnk = (lane & 7) ^ srow;
    const float*  Apf[4];
    const bf16_t* Apb[2];
    const float*  Bpf[4];
    const bf16_t* Bpb[2];
    if constexpr (ABF) {
        const bf16_t* X = (const bf16_t*)Xv;
#pragma unroll
        for (int i = 0; i < 2; i++) {
            int g = w * 2 + i;
            Apb[i] = X + (size_t)(m0 + g * 16 + l15) * NHID + quad * 8;
        }
    } else {
        const float* X = (const float*)Xv;
#pragma unroll
        for (int i = 0; i < 4; i++) {
            int g = w * 4 + i;
            Apf[i] = X + (size_t)(m0 + g * 8 + srow) * NHID + schnk * 4;
        }
    }
    if constexpr (BBF) {
        const bf16_t* Wb = (const bf16_t*)Wselv;
#pragma unroll
        for (int i = 0; i < 2; i++) {
            int g = w * 2 + i;
            Bpb[i] = Wb + (size_t)(n0b + g * 16 + l15) * NHID + quad * 8;
        }
    } else {
        const float* Wf = (const float*)Wselv;
#pragma unroll
        for (int i = 0; i < 4; i++) {
            int g = w * 4 + i;
            Bpf[i] = Wf + (size_t)(n0b + g * 8 + srow) * NHID + schnk * 4;
        }
    }

    auto stage = [&](char* base) {
        char* Ab = base;
        char* Bb = base + ASZ;
        if constexpr (ABF) {
#pragma unroll
            for (int i = 0; i < 2; i++) { gl_lds16(Apb[i], Ab + (w * 2 + i) * 1024); Apb[i] += 32; }
        } else {
#pragma unroll
            for (int i = 0; i < 4; i++) { gl_lds16(Apf[i], Ab + (w * 4 + i) * 1024); Apf[i] += 32; }
        }
        if constexpr (BBF) {
#pragma unroll
            for (int i = 0; i < 2; i++) { gl_lds16(Bpb[i], Bb + (w * 2 + i) * 1024); Bpb[i] += 32; }
        } else {
#pragma unroll
            for (int i = 0; i < 4; i++) { gl_lds16(Bpf[i], Bb + (w * 4 + i) * 1024); Bpf[i] += 32; }
        }
    };

    auto wait_one = [&]() {
        if constexpr (LPS == 4)      asm volatile("s_waitcnt vmcnt(4)" ::: "memory");
        else if constexpr (LPS == 6) asm volatile("s_waitcnt vmcnt(6)" ::: "memory");
        else                         asm volatile("s_waitcnt vmcnt(8)" ::: "memory");
    };

    f32x4 acc[4][4];
#pragma unroll
    for (int i = 0; i < 4; i++)
#pragma unroll
        for (int j = 0; j < 4; j++) acc[i][j] = 0.0f;

    constexpr int KITER = NHID / 32;   // 24
    stage(smem);
    stage(smem + BUFSZ);
    int put = 2, get = 0;

    for (int it = 0; it < KITER; ++it) {
        if (it == KITER - 1) asm volatile("s_waitcnt vmcnt(0)" ::: "memory");
        else                 wait_one();
        __builtin_amdgcn_s_barrier();
        if (it + 2 < KITER) {
            stage(smem + put * BUFSZ);
            put = (put == 2) ? 0 : put + 1;
        }

        char* Ab = smem + get * BUFSZ;
        char* Bb = Ab + ASZ;
        get = (get == 2) ? 0 : get + 1;

        bf16x8 af[4], bfr[4];
        const int pl = (2 * quad) ^ (l15 & 7);
#pragma unroll
        for (int i = 0; i < 4; i++) {
            if constexpr (ABF) {
                int mt = wm * 4 + i;
                af[i] = *(const bf16x8*)(Ab + (mt * 64 + lane) * 16);
            } else {
                int R = (wm * 4 + i) * 16 + l15;
                f32x4 lo = *(const f32x4*)(Ab + R * 128 + pl * 16);
                f32x4 hi = *(const f32x4*)(Ab + R * 128 + (pl ^ 1) * 16);
                af[i] = cvt8(lo, hi);
            }
        }
#pragma unroll
        for (int j = 0; j < 4; j++) {
            if constexpr (BBF) {
                int ntj = wn * 4 + j;
                bfr[j] = *(const bf16x8*)(Bb + (ntj * 64 + lane) * 16);
            } else {
                int R = (wn * 4 + j) * 16 + l15;
                f32x4 lo = *(const f32x4*)(Bb + R * 128 + pl * 16);
                f32x4 hi = *(const f32x4*)(Bb + R * 128 + (pl ^ 1) * 16);
                bfr[j] = cvt8(lo, hi);
            }
        }
#pragma unroll
        for (int i = 0; i < 4; i++)
#pragma unroll
            for (int j = 0; j < 4; j++)
                acc[i][j] = MFMA(af[i], bfr[j], acc[i][j]);
    }

#pragma unroll
    for (int i = 0; i < 4; i++) {
#pragma unroll
        for (int j = 0; j < 4; j++) {
            const int n = n0 + wn * 64 + j * 16 + l15;
            float bn;
            if (MODE == 1) bn = (n < 768) ? bias0[n] : bias1[n - 768];
            else           bn = bias0[n];
            if (MODE == 1 && n >= 768) {
                // Vp layout, bf16x4-packed (rg -> consecutive e-slots)
                const int m = m0 + wm * 64 + i * 16 + quad * 4;
                int b = m / (NA * NS);
                int rem = m - b * (NA * NS);
                int a = rem >> 10, s = rem & 1023;
                int hh = (n - 768) >> 6;
                bf16x4 pk;
#pragma unroll
                for (int rg = 0; rg < 4; rg++) pk[rg] = (bf16_t)(acc[i][j][rg] + bn);
                char* dst = (char*)out1 + (size_t)((b * NHEADS + hh) * NA + a) * 131072
                            + (size_t)(s >> 5) * 4096 + j * 1024
                            + (quad * 16 + l15) * 16 + (i & 1) * 8;
                *reinterpret_cast<bf16x4*>(dst) = pk;
            } else {
#pragma unroll
                for (int rg = 0; rg < 4; rg++) {
                    const int m = m0 + wm * 64 + i * 16 + quad * 4 + rg;
                    float v = acc[i][j][rg] + bn;
                    if (MODE == 0) {
                        int b = m >> 10, s = m & 1023, hh = n >> 6, d = n & 63;
                        out0[(((size_t)(b * NHEADS + hh) * NS) + s) * HD + d] = (bf16_t)v;
                    } else if (MODE == 1) {
                        int b = m / (NA * NS);
                        int rem = m - b * (NA * NS);
                        int a = rem >> 10, s = rem & 1023;
                        int hh = n >> 6, d = n & 63;
                        out0[((((size_t)(b * NHEADS + hh) * NA + a) * NS) + s) * HD + d] = (bf16_t)v;
                    } else {
                        v += resid[(size_t)m * NHID + n];
                        outf[(size_t)m * NHID + n] = v;
                    }
                }
            }
        }
    }
}

// ---------------------------------------------------------------------------
// Attention: block = (bh, 64 q-rows); each WAVE owns a distinct 16-row
// q-tile. Swapped QK^T (MFMA(K,Q)); softmax + bf16 pack fully in-register;
// Vp layout makes V staging contiguous 1KB reads per (a,dt) instr and
// matches P's k-order. LDS 48KB => 3 blocks/CU.
// ---------------------------------------------------------------------------
__global__ __launch_bounds__(256, 3) void attn_kernel(
    const bf16_t* __restrict__ Q, const bf16_t* __restrict__ K,
    const bf16_t* __restrict__ VT, bf16_t* __restrict__ AT)
{
    __shared__ __align__(16) char kv[2 * 24576];        // 2 x (K 12K + V 12K)

    const int t    = threadIdx.x;
    const int w    = t >> 6, lane = t & 63;
    const int quad = lane >> 4, l15 = lane & 15;

    int bh, qt;
    if (gridDim.x == 768) {           // full launch: XCD-local bh
        int xcd = blockIdx.x & 7, j = blockIdx.x >> 3;
        bh = (j >> 4) * 8 + xcd;      // 6 slabs x 8 xcd = 48
        qt = ((j & 15) << 2) | w;     // wave-level q-tiling: 0..63
    } else {                          // per-batch fallback
        bh = blockIdx.x >> 4;
        qt = ((blockIdx.x & 15) << 2) | w;
    }
    const int b  = bh / NHEADS, h = bh - b * NHEADS;
    const int q0 = qt * 16;

    const bf16_t* Qb = Q + ((size_t)bh * NS + q0) * HD;
    bf16x8 qf0 = load8(Qb + l15 * HD + quad * 8);
    bf16x8 qf1 = load8(Qb + l15 * HD + quad * 8 + 32);

    // hoisted staging pointers: 6 groups per wave (24 total: 12 K + 12 V)
    const char* gp[6];
    int gdelta[6], loff[6];
#pragma unroll
    for (int i = 0; i < 6; i++) {
        int g = w * 6 + i;
        loff[i] = g >= 12 ? 12288 + (g - 12) * 1024 : g * 1024;
        if (g < 12) {   // K: a|j|dh
            int a = g >> 2, j = (g >> 1) & 1, dh = g & 1;
            gp[i] = (const char*)(K + ((size_t)(bh * NA + a) * NS + j * 16 + l15) * HD
                                  + dh * 32 + quad * 8);
            gdelta[i] = 32 * HD * 2;  // +32 s-rows (bytes)
        } else {        // Vp: a|dt -- contiguous 1KB per instr
            int gi = g - 12;
            int a = gi >> 2, dt = gi & 3;
            gp[i] = (const char*)VT + (size_t)(bh * NA + a) * 131072
                    + dt * 1024 + (size_t)lane * 16;
            gdelta[i] = 4096;         // next sb (32 s)
        }
    }

    auto stage = [&](int buf) {
#pragma unroll
        for (int i = 0; i < 6; i++) {
            gl_lds16(gp[i], kv + buf * 24576 + loff[i]);
            gp[i] += gdelta[i];
        }
    };

    f32x4 acc[4];
#pragma unroll
    for (int dt = 0; dt < 4; dt++) acc[dt] = 0.0f;

    const float KS = 0.18033688011112042f;  // (1/8) * log2(e)

    stage(0);
    __syncthreads();

    for (int it = 0; it < 32; ++it) {
        if (it + 1 < 32) stage((it + 1) & 1);

        const char* base = kv + (it & 1) * 24576;
        // swapped QK^T: D[row=s][col=q]; lane: q = l15, s = j*16 + quad*4+rg
        f32x4 sc[3][2];
#pragma unroll
        for (int a = 0; a < 3; a++) {
#pragma unroll
            for (int j = 0; j < 2; j++) {
                bf16x8 klo = *(const bf16x8*)(base + ((a * 4 + j * 2 + 0) * 64 + lane) * 16);
                bf16x8 khi = *(const bf16x8*)(base + ((a * 4 + j * 2 + 1) * 64 + lane) * 16);
                f32x4 z = 0.0f;
                f32x4 c0 = MFMA(klo, qf0, z);
                sc[a][j] = MFMA(khi, qf1, c0);
            }
        }
        // 3-exp softmax over adapters, fully in-register
        f32x4 plo[3], phi[3];
#pragma unroll
        for (int j = 0; j < 2; j++) {
#pragma unroll
            for (int rg = 0; rg < 4; rg++) {
                float x0 = sc[0][j][rg], x1 = sc[1][j][rg], x2 = sc[2][j][rg];
                float mx = fmaxf(x0, fmaxf(x1, x2));
                float e0 = __builtin_amdgcn_exp2f((x0 - mx) * KS);
                float e1 = __builtin_amdgcn_exp2f((x1 - mx) * KS);
                float e2 = __builtin_amdgcn_exp2f((x2 - mx) * KS);
                float inv = __builtin_amdgcn_rcpf(e0 + e1 + e2);
                if (j == 0) {
                    plo[0][rg] = e0 * inv; plo[1][rg] = e1 * inv; plo[2][rg] = e2 * inv;
                } else {
                    phi[0][rg] = e0 * inv; phi[1][rg] = e1 * inv; phi[2][rg] = e2 * inv;
                }
            }
        }
        // PV: P packed in-register; k-order matches Vp fragments.
#pragma unroll
        for (int a = 0; a < 3; a++) {
            bf16x8 pf = cvt8(plo[a], phi[a]);
#pragma unroll
            for (int dt = 0; dt < 4; dt++) {
                bf16x8 vf = *(const bf16x8*)(base + 12288 + ((a * 4 + dt) * 64 + lane) * 16);
                acc[dt] = MFMA(pf, vf, acc[dt]);
            }
        }
        __syncthreads();  // guards buffer reuse; drains it+1 staging
    }

    bf16_t* Ob = AT + (size_t)b * NS * NHID;
#pragma unroll
    for (int dt = 0; dt < 4; dt++) {
#pragma unroll
        for (int rg = 0; rg < 4; rg++) {
            int qq = q0 + quad * 4 + rg;
            Ob[(size_t)qq * NHID + h * HD + dt * 16 + l15] = (bf16_t)acc[dt][rg];
        }
    }
}

// ---------------------------------------------------------------------------
// LayerNorm over rows of X (fp32, [4096,768]), IN PLACE.
// ---------------------------------------------------------------------------
__global__ __launch_bounds__(256) void ln_kernel(
    float* __restrict__ X, const float* __restrict__ gamma,
    const float* __restrict__ beta)
{
    const int row = blockIdx.x;
    const int t = threadIdx.x;
    float* x = X + (size_t)row * NHID;
    float v0 = x[t], v1 = x[t + 256], v2 = x[t + 512];
    float s  = v0 + v1 + v2;
    float s2 = v0 * v0 + v1 * v1 + v2 * v2;
#pragma unroll
    for (int off = 32; off > 0; off >>= 1) {
        s  += __shfl_down(s, off);
        s2 += __shfl_down(s2, off);
    }
    __shared__ float red[8];
    const int w = t >> 6, lane = t & 63;
    if (lane == 0) { red[w] = s; red[4 + w] = s2; }
    __syncthreads();
    s  = red[0] + red[1] + red[2] + red[3];
    s2 = red[4] + red[5] + red[6] + red[7];
    float mu  = s * (1.0f / NHID);
    float var = s2 * (1.0f / NHID) - mu * mu;
    float rs  = rsqrtf(fmaxf(var, 0.0f) + 1e-5f);
    x[t]       = (v0 - mu) * rs * gamma[t]       + beta[t];
    x[t + 256] = (v1 - mu) * rs * gamma[t + 256] + beta[t + 256];
    x[t + 512] = (v2 - mu) * rs * gamma[t + 512] + beta[t + 512];
}

// avg_weights == 1/3 identically (softmax over adapter axis sums to 1).
__global__ __launch_bounds__(256) void fill_third(float* __restrict__ p)
{
    const int i = blockIdx.x * 256 + threadIdx.x;
    f32x4 v = { 1.0f / 3.0f, 1.0f / 3.0f, 1.0f / 3.0f, 1.0f / 3.0f };
    *reinterpret_cast<f32x4*>(p + (size_t)i * 4) = v;
}

// ---------------------------------------------------------------------------
// out0 [0,12.58MB) fp32: O-proj X -> LN in place. out1: bf16 scratch
// (Q 6.29 + AT 6.29 MB + tier-2 W spare), overwritten by fill_third last.
// ws tier 1 (>=67,633,152 B): K 18.87 | Vp 18.87 | adaptb 18.87 | Wqb/Wkb/
// Wvb/Wob 1.18 ea | queryb 6.29 MB. tier 2 (>=37,748,736): K | Vp only,
// Wq/Wk/Wv bf16 in out1 spare, A stays fp32.
// ---------------------------------------------------------------------------
extern "C" void kernel_launch(void* const* d_in, const int* in_sizes, int n_in,
                              void* d_out, int out_size, void* d_ws, size_t ws_size,
                              hipStream_t stream)
{
    (void)in_sizes; (void)n_in; (void)out_size;
    const float* query = (const float*)d_in[0];
    const float* adapt = (const float*)d_in[1];
    const float* Wq    = (const float*)d_in[2];
    const float* bq    = (const float*)d_in[3];
    const float* Wk    = (const float*)d_in[4];
    const float* bk    = (const float*)d_in[5];
    const float* Wv    = (const float*)d_in[6];
    const float* bv    = (const float*)d_in[7];
    const float* Wo    = (const float*)d_in[8];
    const float* bo    = (const float*)d_in[9];
    const float* gamma = (const float*)d_in[10];
    const float* beta  = (const float*)d_in[11];

    float*  out0  = (float*)d_out;            // 3,145,728 fp32
    float*  out1f = out0 + 3145728;           // 4,194,304 fp32
    bf16_t* out1b = (bf16_t*)out1f;

    dim3 blk(256);

    if (ws_size >= (size_t)67633152) {
        // ---- tier 1: full bf16 pipeline, barrier-free wave GEMMs ----
        bf16_t* Kw  = (bf16_t*)d_ws;
        bf16_t* VTw = (bf16_t*)((char*)d_ws + 18874368);
        bf16_t* Adb = (bf16_t*)((char*)d_ws + 37748736);   // adapt bf16
        bf16_t* Wqb = (bf16_t*)((char*)d_ws + 56623104);
        bf16_t* Wkb = (bf16_t*)((char*)d_ws + 57802752);
        bf16_t* Wvb = (bf16_t*)((char*)d_ws + 58982400);
        bf16_t* Wob = (bf16_t*)((char*)d_ws + 60162048);
        bf16_t* Qcb = (bf16_t*)((char*)d_ws + 61341696);   // query bf16
        bf16_t* Qw  = out1b;
        bf16_t* ATw = out1b + 3145728;
        // bulk fp32->bf16: adapt 2304 | query 768 | Wq/Wk/Wv/Wo 144 each
        cvt6<<<dim3(3648), blk, 0, stream>>>(
            adapt, Adb, 2304, query, Qcb, 3072,
            Wq, Wqb, 3216, Wk, Wkb, 3360, Wv, Wvb, 3504, Wo, Wob, 3648);
        // merged QKV: 4608 KV wave-blocks + 768 Q wave-blocks
        wgemm<4, 24><<<dim3(5376), dim3(64), 0, stream>>>(
            Adb, Wkb, Wvb, bk, bv, nullptr, Kw, VTw, nullptr,
            Qcb, Wqb, bq, Qw);
        attn_kernel<<<dim3(768), blk, 0, stream>>>(Qw, Kw, VTw, ATw);
        wgemm<3, 12><<<dim3(768), dim3(64), 0, stream>>>(
            ATw, Wob, nullptr, bo, nullptr, query, nullptr, nullptr, out0,
            nullptr, nullptr, nullptr, nullptr);
    } else if (ws_size >= (size_t)37748736) {
        // ---- tier 2: bf16 B only (W's in out1 spare), fp32 A ----
        bf16_t* Kw  = (bf16_t*)d_ws;
        bf16_t* VTw = (bf16_t*)((char*)d_ws + 18874368);
        bf16_t* Qw  = out1b;
        bf16_t* ATw = out1b + 3145728;
        bf16_t* Wqb = out1b + 6291456;         // 4.19MB spare in out1
        bf16_t* Wkb = Wqb + 589824;
        bf16_t* Wvb = Wkb + 589824;
        cvt6<<<dim3(432), blk, 0, stream>>>(
            Wq, Wqb, 144, Wk, Wkb, 288, Wv, Wvb, 432,
            Wv, Wvb, 432, Wv, Wvb, 432, Wv, Wvb, 432);
        proj_gemm<0, 6, false, true><<<dim3(192), blk, 0, stream>>>(
            query, Wqb, nullptr, bq, nullptr, nullptr, Qw, nullptr, nullptr);
        proj_gemm<1, 12, false, true><<<dim3(1152), blk, 0, stream>>>(
            adapt, Wkb, Wvb, bk, bv, nullptr, Kw, VTw, nullptr);
        attn_kernel<<<dim3(768), blk, 0, stream>>>(Qw, Kw, VTw, ATw);
        proj_gemm<3, 6, true, false><<<dim3(192), blk, 0, stream>>>(
            ATw, Wo, nullptr, bo, nullptr, query, nullptr, nullptr, out0);
    } else {
        // per-batch, zero-workspace fallback (scratch inside out1)
        bf16_t* Qc  = out1b;                  //   786,432 bf16
        bf16_t* ATc = out1b + 786432;         //   786,432 bf16
        bf16_t* Kc  = out1b + 1572864;        // 2,359,296 bf16
        bf16_t* VTc = out1b + 3932160;        // 2,359,296 bf16
        for (int b = 0; b < NB; b++) {
            const float* qb = query + (size_t)b * NS * NHID;
            const float* ab = adapt + (size_t)b * NA * NS * NHID;
            proj_gemm<0, 6, false, false><<<dim3(48), blk, 0, stream>>>(
                qb, Wq, nullptr, bq, nullptr, nullptr, Qc, nullptr, nullptr);
            proj_gemm<1, 12, false, false><<<dim3(288), blk, 0, stream>>>(
                ab, Wk, Wv, bk, bv, nullptr, Kc, VTc, nullptr);
            attn_kernel<<<dim3(192), blk, 0, stream>>>(Qc, Kc, VTc, ATc);
            proj_gemm<3, 6, true, false><<<dim3(48), blk, 0, stream>>>(
                ATc, Wo, nullptr, bo, nullptr, qb, nullptr, nullptr,
                out0 + (size_t)b * NS * NHID);
        }
    }

    ln_kernel<<<dim3(4096), blk, 0, stream>>>(out0, gamma, beta);
    fill_third<<<dim3(4096), blk, 0, stream>>>(out1f);
}

// Round 5
// 287.941 us; speedup vs baseline: 1.1332x; 1.1332x over previous
//
#include <hip/hip_runtime.h>

// Problem constants
#define NB 4
#define NA 3
#define NS 1024
#define NHID 768
#define NHEADS 12
#define HD 64

typedef __bf16 bf16_t;
typedef __bf16 bf16x8 __attribute__((ext_vector_type(8)));
typedef __bf16 bf16x4 __attribute__((ext_vector_type(4)));
typedef float f32x4 __attribute__((ext_vector_type(4)));

#define MFMA(a, b, c) __builtin_amdgcn_mfma_f32_16x16x32_bf16(a, b, c, 0, 0, 0)

static __device__ __forceinline__ bf16x8 load8(const bf16_t* p) {
    return *reinterpret_cast<const bf16x8*>(p);
}

// async global->LDS, 16B per lane. LDS dest = wave-uniform base + lane*16.
typedef __attribute__((address_space(3))) unsigned int u32_lds;
typedef __attribute__((address_space(1))) unsigned int u32_glb;
static __device__ __forceinline__ void gl_lds16(const void* g, void* lds_base_uniform) {
    __builtin_amdgcn_global_load_lds((const u32_glb*)g, (u32_lds*)lds_base_uniform, 16, 0, 0);
}

static __device__ __forceinline__ bf16x8 cvt8(f32x4 lo, f32x4 hi) {
    bf16x8 r;
    r[0] = (bf16_t)lo[0]; r[1] = (bf16_t)lo[1]; r[2] = (bf16_t)lo[2]; r[3] = (bf16_t)lo[3];
    r[4] = (bf16_t)hi[0]; r[5] = (bf16_t)hi[1]; r[6] = (bf16_t)hi[2]; r[7] = (bf16_t)hi[3];
    return r;
}

// ---------------------------------------------------------------------------
// Vp layout (validated by R14 pass): per (bh,a): 32 sb-blocks of 4KB:
//   byte = (bh*NA+a)*131072 + sb*4096 + dt*1024 + (q*16 + l)*16 + e*2
// holding V[d = dt*16+l][s = sb*32 + s5] with s5 = (e>>2)*16 + q*4 + (e&3).
// attn's V staging is a contiguous 1KB read per (a,dt) instr, and the
// k-order matches the swapped-QK P fragment exactly.
// ---------------------------------------------------------------------------

// ---------------------------------------------------------------------------
// fp32 -> bf16 bulk conversion, up to 6 segments. Each block handles 4096
// elems (256 thr x 4 x f32x4). cN are CUMULATIVE block boundaries.
// ---------------------------------------------------------------------------
__global__ __launch_bounds__(256) void cvt6(
    const float* __restrict__ s0, bf16_t* __restrict__ d0, int c0,
    const float* __restrict__ s1, bf16_t* __restrict__ d1, int c1,
    const float* __restrict__ s2, bf16_t* __restrict__ d2, int c2,
    const float* __restrict__ s3, bf16_t* __restrict__ d3, int c3,
    const float* __restrict__ s4, bf16_t* __restrict__ d4, int c4,
    const float* __restrict__ s5, bf16_t* __restrict__ d5, int c5)
{
    const int bid = blockIdx.x;
    const float* s; bf16_t* d; int rel;
    if      (bid < c0) { s = s0; d = d0; rel = bid; }
    else if (bid < c1) { s = s1; d = d1; rel = bid - c0; }
    else if (bid < c2) { s = s2; d = d2; rel = bid - c1; }
    else if (bid < c3) { s = s3; d = d3; rel = bid - c2; }
    else if (bid < c4) { s = s4; d = d4; rel = bid - c3; }
    else               { s = s5; d = d5; rel = bid - c4; }
    const int t = threadIdx.x;
#pragma unroll
    for (int k = 0; k < 4; k++) {
        size_t u = (size_t)rel * 1024 + k * 256 + t;   // f32x4 unit index
        f32x4 v = reinterpret_cast<const f32x4*>(s)[u];
        bf16x4 o;
        o[0] = (bf16_t)v[0]; o[1] = (bf16_t)v[1];
        o[2] = (bf16_t)v[2]; o[3] = (bf16_t)v[3];
        reinterpret_cast<bf16x4*>(d)[u] = o;
    }
}

// ---------------------------------------------------------------------------
// Projection GEMM, 128x128 tile, BK=32, 4 waves (2x2) of 64x64 (4x4 MFMA).
// R15: 2 buffers + 2 RAW barriers + counted vmcnt (never drains in-loop).
// Per iter: stage(it+1) -> vmcnt(LPS) [stage(it) landed, it+1 in flight]
// -> s_barrier -> ds_read+MFMA -> s_barrier (raw, no drain; reuse safety =
// parity + MFMA's auto-lgkmcnt retiring all ds_reads pre-barrier).
// LDS 32KB (all-bf16) => 5 blocks/CU = 20 waves (R13's 3-buf was 12).
// XCD swizzle: all NT n-tiles of one m-slab on one XCD (bid&7).
// MODE 0: Q bf16 [b][h][s][d]
// MODE 1: fused KV, N=1536: n<768 -> K [b][h][a][s][d]; n>=768 -> Vp
// MODE 3: fp32 outf = gemm + bias + resid
// MODE 4: merged QKV: blocks [0,1152) = MODE1 KV; [1152,1344) = MODE0 Q via
//         (X2, W2v, bias2, out2). 1152%8==0 keeps XCD swizzle intact.
// ---------------------------------------------------------------------------
template <int MODE, int NT, bool ABF, bool BBF>
__global__ __launch_bounds__(256) void proj_gemm(
    const void* __restrict__ Xv,
    const void* __restrict__ W0v, const void* __restrict__ W1v,
    const float* __restrict__ bias0, const float* __restrict__ bias1,
    const float* __restrict__ resid,
    bf16_t* __restrict__ out0, bf16_t* __restrict__ out1,
    float* __restrict__ outf,
    const void* __restrict__ X2, const void* __restrict__ W2v,
    const float* __restrict__ bias2, bf16_t* __restrict__ out2)
{
    constexpr int ASZ   = ABF ? 8192 : 16384;
    constexpr int BSZ   = BBF ? 8192 : 16384;
    constexpr int BUFSZ = ASZ + BSZ;
    constexpr int LPS   = (ABF ? 2 : 4) + (BBF ? 2 : 4);
    __shared__ __align__(16) char smem[2 * BUFSZ];

    const int t = threadIdx.x;
    const int lane = t & 63, w = t >> 6;
    const int quad = lane >> 4, l15 = lane & 15;
    const int wm = w >> 1, wn = w & 1;

    // merged-mode block remap (block-uniform)
    int emode = (MODE == 4) ? 1 : MODE;
    int nt    = NT;
    int bid   = blockIdx.x;
    const void*  Xp  = Xv;
    const void*  W0p = W0v;
    const float* b0  = bias0;
    bf16_t*      o0  = out0;
    if constexpr (MODE == 4) {
        if (bid >= 1152) {
            emode = 0; nt = 6; bid -= 1152;
            Xp = X2; W0p = W2v; b0 = bias2; o0 = out2;
        }
    }

    // XCD-aware swizzle (bijective index remap)
    const int xcd = bid & 7, jj = bid >> 3;
    const int n_t = jj % nt, slab = jj / nt;
    const int m0 = (slab * 8 + xcd) * 128;
    const int n0 = n_t * 128;

    // B source select (KV fusion)
    const void* Wselv = (emode == 1 && n0 >= 768) ? W1v : W0p;
    const int n0b = (emode == 1 && n0 >= 768) ? n0 - 768 : n0;

    // hoisted staging pointers
    const int srow  = lane >> 3;                 // row within 8-row group
    const int schnk = (lane & 7) ^ srow;         // XOR'd 16B chunk position
    const float*  Apf[4];
    const bf16_t* Apb[2];
    const float*  Bpf[4];
    const bf16_t* Bpb[2];
    if constexpr (ABF) {
        const bf16_t* X = (const bf16_t*)Xp;
#pragma unroll
        for (int i = 0; i < 2; i++) {
            int g = w * 2 + i;                   // chunk-major bf16 (proven)
            Apb[i] = X + (size_t)(m0 + g * 16 + l15) * NHID + quad * 8;
        }
    } else {
        const float* X = (const float*)Xp;
#pragma unroll
        for (int i = 0; i < 4; i++) {
            int g = w * 4 + i;                   // row-major XOR fp32
            Apf[i] = X + (size_t)(m0 + g * 8 + srow) * NHID + schnk * 4;
        }
    }
    if constexpr (BBF) {
        const bf16_t* Wb = (const bf16_t*)Wselv;
#pragma unroll
        for (int i = 0; i < 2; i++) {
            int g = w * 2 + i;
            Bpb[i] = Wb + (size_t)(n0b + g * 16 + l15) * NHID + quad * 8;
        }
    } else {
        const float* Wf = (const float*)Wselv;
#pragma unroll
        for (int i = 0; i < 4; i++) {
            int g = w * 4 + i;
            Bpf[i] = Wf + (size_t)(n0b + g * 8 + srow) * NHID + schnk * 4;
        }
    }

    // stage one 32-k tile into buffer `base`, advancing pointers
    auto stage = [&](char* base) {
        char* Ab = base;
        char* Bb = base + ASZ;
        if constexpr (ABF) {
#pragma unroll
            for (int i = 0; i < 2; i++) { gl_lds16(Apb[i], Ab + (w * 2 + i) * 1024); Apb[i] += 32; }
        } else {
#pragma unroll
            for (int i = 0; i < 4; i++) { gl_lds16(Apf[i], Ab + (w * 4 + i) * 1024); Apf[i] += 32; }
        }
        if constexpr (BBF) {
#pragma unroll
            for (int i = 0; i < 2; i++) { gl_lds16(Bpb[i], Bb + (w * 2 + i) * 1024); Bpb[i] += 32; }
        } else {
#pragma unroll
            for (int i = 0; i < 4; i++) { gl_lds16(Bpf[i], Bb + (w * 4 + i) * 1024); Bpf[i] += 32; }
        }
    };

    auto wait_one = [&]() {   // allow one stage (LPS loads) outstanding
        if constexpr (LPS == 4)      asm volatile("s_waitcnt vmcnt(4)" ::: "memory");
        else if constexpr (LPS == 6) asm volatile("s_waitcnt vmcnt(6)" ::: "memory");
        else                         asm volatile("s_waitcnt vmcnt(8)" ::: "memory");
    };

    f32x4 acc[4][4];
#pragma unroll
    for (int i = 0; i < 4; i++)
#pragma unroll
        for (int j = 0; j < 4; j++) acc[i][j] = 0.0f;

    constexpr int KITER = NHID / 32;   // 24
    stage(smem);

    for (int it = 0; it < KITER; ++it) {
        if (it + 1 < KITER) {
            stage(smem + ((it + 1) & 1) * BUFSZ);   // prefetch into other buf
            wait_one();                              // stage(it) landed
        } else {
            asm volatile("s_waitcnt vmcnt(0)" ::: "memory");
        }
        __builtin_amdgcn_s_barrier();               // all waves' stage(it) done

        char* Ab = smem + (it & 1) * BUFSZ;
        char* Bb = Ab + ASZ;

        bf16x8 af[4], bfr[4];
        const int pl = (2 * quad) ^ (l15 & 7);
#pragma unroll
        for (int i = 0; i < 4; i++) {
            if constexpr (ABF) {
                int mt = wm * 4 + i;
                af[i] = *(const bf16x8*)(Ab + (mt * 64 + lane) * 16);
            } else {
                int R = (wm * 4 + i) * 16 + l15;
                f32x4 lo = *(const f32x4*)(Ab + R * 128 + pl * 16);
                f32x4 hi = *(const f32x4*)(Ab + R * 128 + (pl ^ 1) * 16);
                af[i] = cvt8(lo, hi);
            }
        }
#pragma unroll
        for (int j = 0; j < 4; j++) {
            if constexpr (BBF) {
                int ntj = wn * 4 + j;
                bfr[j] = *(const bf16x8*)(Bb + (ntj * 64 + lane) * 16);
            } else {
                int R = (wn * 4 + j) * 16 + l15;
                f32x4 lo = *(const f32x4*)(Bb + R * 128 + pl * 16);
                f32x4 hi = *(const f32x4*)(Bb + R * 128 + (pl ^ 1) * 16);
                bfr[j] = cvt8(lo, hi);
            }
        }
#pragma unroll
        for (int i = 0; i < 4; i++)
#pragma unroll
            for (int j = 0; j < 4; j++)
                acc[i][j] = MFMA(af[i], bfr[j], acc[i][j]);
        // raw barrier: no wave may start iter it+1's stage (overwriting this
        // buffer) until every wave's ds_reads here retired (MFMA data-deps).
        __builtin_amdgcn_s_barrier();
    }

#pragma unroll
    for (int i = 0; i < 4; i++) {
#pragma unroll
        for (int j = 0; j < 4; j++) {
            const int n = n0 + wn * 64 + j * 16 + l15;
            float bn;
            if (emode == 1) bn = (n < 768) ? b0[n] : bias1[n - 768];
            else            bn = b0[n];
            if (emode == 1 && n >= 768) {
                // Vp layout, bf16x4-packed (rg -> consecutive e-slots)
                const int m = m0 + wm * 64 + i * 16 + quad * 4;
                int b = m / (NA * NS);
                int rem = m - b * (NA * NS);
                int a = rem >> 10, s = rem & 1023;
                int hh = (n - 768) >> 6;
                bf16x4 pk;
#pragma unroll
                for (int rg = 0; rg < 4; rg++) pk[rg] = (bf16_t)(acc[i][j][rg] + bn);
                char* dst = (char*)out1 + (size_t)((b * NHEADS + hh) * NA + a) * 131072
                            + (size_t)(s >> 5) * 4096 + j * 1024
                            + (quad * 16 + l15) * 16 + (i & 1) * 8;
                *reinterpret_cast<bf16x4*>(dst) = pk;
            } else {
#pragma unroll
                for (int rg = 0; rg < 4; rg++) {
                    const int m = m0 + wm * 64 + i * 16 + quad * 4 + rg;
                    float v = acc[i][j][rg] + bn;
                    if (emode == 0) {
                        int b = m >> 10, s = m & 1023, hh = n >> 6, d = n & 63;
                        o0[(((size_t)(b * NHEADS + hh) * NS) + s) * HD + d] = (bf16_t)v;
                    } else if (emode == 1) {
                        int b = m / (NA * NS);
                        int rem = m - b * (NA * NS);
                        int a = rem >> 10, s = rem & 1023;
                        int hh = n >> 6, d = n & 63;
                        o0[((((size_t)(b * NHEADS + hh) * NA + a) * NS) + s) * HD + d] = (bf16_t)v;
                    } else {
                        v += resid[(size_t)m * NHID + n];
                        outf[(size_t)m * NHID + n] = v;
                    }
                }
            }
        }
    }
}

// ---------------------------------------------------------------------------
// Attention: block = (bh, 64 q-rows); each WAVE owns a distinct 16-row
// q-tile. Swapped QK^T (MFMA(K,Q)); softmax + bf16 pack fully in-register;
// Vp layout: V staging contiguous, k-order matches P. LDS 48KB => 3
// blocks/CU. R15: counted-vmcnt 2-barrier loop (replaces __syncthreads'
// full vmcnt(0) drain): stage(it+1) -> vmcnt(6) -> barrier -> compute ->
// raw barrier. Next-tile loads stay in flight across the compute phase.
// ---------------------------------------------------------------------------
__global__ __launch_bounds__(256, 3) void attn_kernel(
    const bf16_t* __restrict__ Q, const bf16_t* __restrict__ K,
    const bf16_t* __restrict__ VT, bf16_t* __restrict__ AT)
{
    __shared__ __align__(16) char kv[2 * 24576];        // 2 x (K 12K + V 12K)

    const int t    = threadIdx.x;
    const int w    = t >> 6, lane = t & 63;
    const int quad = lane >> 4, l15 = lane & 15;

    int bh, qt;
    if (gridDim.x == 768) {           // full launch: XCD-local bh
        int xcd = blockIdx.x & 7, j = blockIdx.x >> 3;
        bh = (j >> 4) * 8 + xcd;      // 6 slabs x 8 xcd = 48
        qt = ((j & 15) << 2) | w;     // wave-level q-tiling: 0..63
    } else {                          // per-batch fallback
        bh = blockIdx.x >> 4;
        qt = ((blockIdx.x & 15) << 2) | w;
    }
    const int b  = bh / NHEADS, h = bh - b * NHEADS;
    const int q0 = qt * 16;

    const bf16_t* Qb = Q + ((size_t)bh * NS + q0) * HD;
    bf16x8 qf0 = load8(Qb + l15 * HD + quad * 8);
    bf16x8 qf1 = load8(Qb + l15 * HD + quad * 8 + 32);

    // hoisted staging pointers: 6 groups per wave (24 total: 12 K + 12 V)
    const char* gp[6];
    int gdelta[6], loff[6];
#pragma unroll
    for (int i = 0; i < 6; i++) {
        int g = w * 6 + i;
        loff[i] = g >= 12 ? 12288 + (g - 12) * 1024 : g * 1024;
        if (g < 12) {   // K: a|j|dh
            int a = g >> 2, j = (g >> 1) & 1, dh = g & 1;
            gp[i] = (const char*)(K + ((size_t)(bh * NA + a) * NS + j * 16 + l15) * HD
                                  + dh * 32 + quad * 8);
            gdelta[i] = 32 * HD * 2;  // +32 s-rows (bytes)
        } else {        // Vp: a|dt -- contiguous 1KB per instr
            int gi = g - 12;
            int a = gi >> 2, dt = gi & 3;
            gp[i] = (const char*)VT + (size_t)(bh * NA + a) * 131072
                    + dt * 1024 + (size_t)lane * 16;
            gdelta[i] = 4096;         // next sb (32 s)
        }
    }

    auto stage = [&](int buf) {
#pragma unroll
        for (int i = 0; i < 6; i++) {
            gl_lds16(gp[i], kv + buf * 24576 + loff[i]);
            gp[i] += gdelta[i];
        }
    };

    f32x4 acc[4];
#pragma unroll
    for (int dt = 0; dt < 4; dt++) acc[dt] = 0.0f;

    const float KS = 0.18033688011112042f;  // (1/8) * log2(e)

    stage(0);

    for (int it = 0; it < 32; ++it) {
        if (it + 1 < 32) {
            stage((it + 1) & 1);
            asm volatile("s_waitcnt vmcnt(6)" ::: "memory");  // stage(it) done
        } else {
            asm volatile("s_waitcnt vmcnt(0)" ::: "memory");
        }
        __builtin_amdgcn_s_barrier();

        const char* base = kv + (it & 1) * 24576;
        // swapped QK^T: D[row=s][col=q]; lane: q = l15, s = j*16 + quad*4+rg
        f32x4 sc[3][2];
#pragma unroll
        for (int a = 0; a < 3; a++) {
#pragma unroll
            for (int j = 0; j < 2; j++) {
                bf16x8 klo = *(const bf16x8*)(base + ((a * 4 + j * 2 + 0) * 64 + lane) * 16);
                bf16x8 khi = *(const bf16x8*)(base + ((a * 4 + j * 2 + 1) * 64 + lane) * 16);
                f32x4 z = 0.0f;
                f32x4 c0 = MFMA(klo, qf0, z);
                sc[a][j] = MFMA(khi, qf1, c0);
            }
        }
        // 3-exp softmax over adapters, fully in-register
        f32x4 plo[3], phi[3];
#pragma unroll
        for (int j = 0; j < 2; j++) {
#pragma unroll
            for (int rg = 0; rg < 4; rg++) {
                float x0 = sc[0][j][rg], x1 = sc[1][j][rg], x2 = sc[2][j][rg];
                float mx = fmaxf(x0, fmaxf(x1, x2));
                float e0 = __builtin_amdgcn_exp2f((x0 - mx) * KS);
                float e1 = __builtin_amdgcn_exp2f((x1 - mx) * KS);
                float e2 = __builtin_amdgcn_exp2f((x2 - mx) * KS);
                float inv = __builtin_amdgcn_rcpf(e0 + e1 + e2);
                if (j == 0) {
                    plo[0][rg] = e0 * inv; plo[1][rg] = e1 * inv; plo[2][rg] = e2 * inv;
                } else {
                    phi[0][rg] = e0 * inv; phi[1][rg] = e1 * inv; phi[2][rg] = e2 * inv;
                }
            }
        }
        // PV: P packed in-register; k-order matches Vp fragments.
#pragma unroll
        for (int a = 0; a < 3; a++) {
            bf16x8 pf = cvt8(plo[a], phi[a]);
#pragma unroll
            for (int dt = 0; dt < 4; dt++) {
                bf16x8 vf = *(const bf16x8*)(base + 12288 + ((a * 4 + dt) * 64 + lane) * 16);
                acc[dt] = MFMA(pf, vf, acc[dt]);
            }
        }
        // raw barrier (no drain): guards buffer reuse for stage(it+2)
        __builtin_amdgcn_s_barrier();
    }

    bf16_t* Ob = AT + (size_t)b * NS * NHID;
#pragma unroll
    for (int dt = 0; dt < 4; dt++) {
#pragma unroll
        for (int rg = 0; rg < 4; rg++) {
            int qq = q0 + quad * 4 + rg;
            Ob[(size_t)qq * NHID + h * HD + dt * 16 + l15] = (bf16_t)acc[dt][rg];
        }
    }
}

// ---------------------------------------------------------------------------
// LayerNorm over rows of X (fp32, [4096,768]), IN PLACE.
// ---------------------------------------------------------------------------
__global__ __launch_bounds__(256) void ln_kernel(
    float* __restrict__ X, const float* __restrict__ gamma,
    const float* __restrict__ beta)
{
    const int row = blockIdx.x;
    const int t = threadIdx.x;
    float* x = X + (size_t)row * NHID;
    float v0 = x[t], v1 = x[t + 256], v2 = x[t + 512];
    float s  = v0 + v1 + v2;
    float s2 = v0 * v0 + v1 * v1 + v2 * v2;
#pragma unroll
    for (int off = 32; off > 0; off >>= 1) {
        s  += __shfl_down(s, off);
        s2 += __shfl_down(s2, off);
    }
    __shared__ float red[8];
    const int w = t >> 6, lane = t & 63;
    if (lane == 0) { red[w] = s; red[4 + w] = s2; }
    __syncthreads();
    s  = red[0] + red[1] + red[2] + red[3];
    s2 = red[4] + red[5] + red[6] + red[7];
    float mu  = s * (1.0f / NHID);
    float var = s2 * (1.0f / NHID) - mu * mu;
    float rs  = rsqrtf(fmaxf(var, 0.0f) + 1e-5f);
    x[t]       = (v0 - mu) * rs * gamma[t]       + beta[t];
    x[t + 256] = (v1 - mu) * rs * gamma[t + 256] + beta[t + 256];
    x[t + 512] = (v2 - mu) * rs * gamma[t + 512] + beta[t + 512];
}

// avg_weights == 1/3 identically (softmax over adapter axis sums to 1).
__global__ __launch_bounds__(256) void fill_third(float* __restrict__ p)
{
    const int i = blockIdx.x * 256 + threadIdx.x;
    f32x4 v = { 1.0f / 3.0f, 1.0f / 3.0f, 1.0f / 3.0f, 1.0f / 3.0f };
    *reinterpret_cast<f32x4*>(p + (size_t)i * 4) = v;
}

// ---------------------------------------------------------------------------
// out0 [0,12.58MB) fp32: O-proj X -> LN in place. out1: bf16 scratch
// (Q 6.29 + AT 6.29 MB + tier-2 W spare), overwritten by fill_third last.
// ws tier 1 (>=67,633,152 B): K 18.87 | Vp 18.87 | adaptb 18.87 | Wqb/Wkb/
// Wvb/Wob 1.18 ea | queryb 6.29 MB. tier 2 (>=37,748,736): K | Vp only,
// Wq/Wk/Wv bf16 in out1 spare, A stays fp32.
// ---------------------------------------------------------------------------
extern "C" void kernel_launch(void* const* d_in, const int* in_sizes, int n_in,
                              void* d_out, int out_size, void* d_ws, size_t ws_size,
                              hipStream_t stream)
{
    (void)in_sizes; (void)n_in; (void)out_size;
    const float* query = (const float*)d_in[0];
    const float* adapt = (const float*)d_in[1];
    const float* Wq    = (const float*)d_in[2];
    const float* bq    = (const float*)d_in[3];
    const float* Wk    = (const float*)d_in[4];
    const float* bk    = (const float*)d_in[5];
    const float* Wv    = (const float*)d_in[6];
    const float* bv    = (const float*)d_in[7];
    const float* Wo    = (const float*)d_in[8];
    const float* bo    = (const float*)d_in[9];
    const float* gamma = (const float*)d_in[10];
    const float* beta  = (const float*)d_in[11];

    float*  out0  = (float*)d_out;            // 3,145,728 fp32
    float*  out1f = out0 + 3145728;           // 4,194,304 fp32
    bf16_t* out1b = (bf16_t*)out1f;

    dim3 blk(256);

    if (ws_size >= (size_t)67633152) {
        // ---- tier 1: full bf16 pipeline, counted-vmcnt cooperative GEMMs --
        bf16_t* Kw  = (bf16_t*)d_ws;
        bf16_t* VTw = (bf16_t*)((char*)d_ws + 18874368);
        bf16_t* Adb = (bf16_t*)((char*)d_ws + 37748736);   // adapt bf16
        bf16_t* Wqb = (bf16_t*)((char*)d_ws + 56623104);
        bf16_t* Wkb = (bf16_t*)((char*)d_ws + 57802752);
        bf16_t* Wvb = (bf16_t*)((char*)d_ws + 58982400);
        bf16_t* Wob = (bf16_t*)((char*)d_ws + 60162048);
        bf16_t* Qcb = (bf16_t*)((char*)d_ws + 61341696);   // query bf16
        bf16_t* Qw  = out1b;
        bf16_t* ATw = out1b + 3145728;
        // bulk fp32->bf16: adapt 2304 | query 768 | Wq/Wk/Wv/Wo 144 each
        cvt6<<<dim3(3648), blk, 0, stream>>>(
            adapt, Adb, 2304, query, Qcb, 3072,
            Wq, Wqb, 3216, Wk, Wkb, 3360, Wv, Wvb, 3504, Wo, Wob, 3648);
        // merged QKV: 1152 KV blocks + 192 Q blocks
        proj_gemm<4, 12, true, true><<<dim3(1344), blk, 0, stream>>>(
            Adb, Wkb, Wvb, bk, bv, nullptr, Kw, VTw, nullptr,
            Qcb, Wqb, bq, Qw);
        attn_kernel<<<dim3(768), blk, 0, stream>>>(Qw, Kw, VTw, ATw);
        proj_gemm<3, 6, true, true><<<dim3(192), blk, 0, stream>>>(
            ATw, Wob, nullptr, bo, nullptr, query, nullptr, nullptr, out0,
            nullptr, nullptr, nullptr, nullptr);
    } else if (ws_size >= (size_t)37748736) {
        // ---- tier 2: bf16 B only (W's in out1 spare), fp32 A ----
        bf16_t* Kw  = (bf16_t*)d_ws;
        bf16_t* VTw = (bf16_t*)((char*)d_ws + 18874368);
        bf16_t* Qw  = out1b;
        bf16_t* ATw = out1b + 3145728;
        bf16_t* Wqb = out1b + 6291456;         // 4.19MB spare in out1
        bf16_t* Wkb = Wqb + 589824;
        bf16_t* Wvb = Wkb + 589824;
        cvt6<<<dim3(432), blk, 0, stream>>>(
            Wq, Wqb, 144, Wk, Wkb, 288, Wv, Wvb, 432,
            Wv, Wvb, 432, Wv, Wvb, 432, Wv, Wvb, 432);
        proj_gemm<0, 6, false, true><<<dim3(192), blk, 0, stream>>>(
            query, Wqb, nullptr, bq, nullptr, nullptr, Qw, nullptr, nullptr,
            nullptr, nullptr, nullptr, nullptr);
        proj_gemm<1, 12, false, true><<<dim3(1152), blk, 0, stream>>>(
            adapt, Wkb, Wvb, bk, bv, nullptr, Kw, VTw, nullptr,
            nullptr, nullptr, nullptr, nullptr);
        attn_kernel<<<dim3(768), blk, 0, stream>>>(Qw, Kw, VTw, ATw);
        proj_gemm<3, 6, true, false><<<dim3(192), blk, 0, stream>>>(
            ATw, Wo, nullptr, bo, nullptr, query, nullptr, nullptr, out0,
            nullptr, nullptr, nullptr, nullptr);
    } else {
        // per-batch, zero-workspace fallback (scratch inside out1)
        bf16_t* Qc  = out1b;                  //   786,432 bf16
        bf16_t* ATc = out1b + 786432;         //   786,432 bf16
        bf16_t* Kc  = out1b + 1572864;        // 2,359,296 bf16
        bf16_t* VTc = out1b + 3932160;        // 2,359,296 bf16
        for (int b = 0; b < NB; b++) {
            const float* qb = query + (size_t)b * NS * NHID;
            const float* ab = adapt + (size_t)b * NA * NS * NHID;
            proj_gemm<0, 6, false, false><<<dim3(48), blk, 0, stream>>>(
                qb, Wq, nullptr, bq, nullptr, nullptr, Qc, nullptr, nullptr,
                nullptr, nullptr, nullptr, nullptr);
            proj_gemm<1, 12, false, false><<<dim3(288), blk, 0, stream>>>(
                ab, Wk, Wv, bk, bv, nullptr, Kc, VTc, nullptr,
                nullptr, nullptr, nullptr, nullptr);
            attn_kernel<<<dim3(192), blk, 0, stream>>>(Qc, Kc, VTc, ATc);
            proj_gemm<3, 6, true, false><<<dim3(48), blk, 0, stream>>>(
                ATc, Wo, nullptr, bo, nullptr, qb, nullptr, nullptr,
                out0 + (size_t)b * NS * NHID,
                nullptr, nullptr, nullptr, nullptr);
        }
    }

    ln_kernel<<<dim3(4096), blk, 0, stream>>>(out0, gamma, beta);
    fill_third<<<dim3(4096), blk, 0, stream>>>(out1f);
}

// Round 6
// 284.427 us; speedup vs baseline: 1.1472x; 1.0124x over previous
//
#include <hip/hip_runtime.h>

// Problem constants
#define NB 4
#define NA 3
#define NS 1024
#define NHID 768
#define NHEADS 12
#define HD 64

typedef __bf16 bf16_t;
typedef __bf16 bf16x8 __attribute__((ext_vector_type(8)));
typedef __bf16 bf16x4 __attribute__((ext_vector_type(4)));
typedef float f32x4 __attribute__((ext_vector_type(4)));

#define MFMA(a, b, c) __builtin_amdgcn_mfma_f32_16x16x32_bf16(a, b, c, 0, 0, 0)

static __device__ __forceinline__ bf16x8 load8(const bf16_t* p) {
    return *reinterpret_cast<const bf16x8*>(p);
}

// async global->LDS, 16B per lane. LDS dest = wave-uniform base + lane*16.
typedef __attribute__((address_space(3))) unsigned int u32_lds;
typedef __attribute__((address_space(1))) unsigned int u32_glb;
static __device__ __forceinline__ void gl_lds16(const void* g, void* lds_base_uniform) {
    __builtin_amdgcn_global_load_lds((const u32_glb*)g, (u32_lds*)lds_base_uniform, 16, 0, 0);
}

static __device__ __forceinline__ bf16x8 cvt8(f32x4 lo, f32x4 hi) {
    bf16x8 r;
    r[0] = (bf16_t)lo[0]; r[1] = (bf16_t)lo[1]; r[2] = (bf16_t)lo[2]; r[3] = (bf16_t)lo[3];
    r[4] = (bf16_t)hi[0]; r[5] = (bf16_t)hi[1]; r[6] = (bf16_t)hi[2]; r[7] = (bf16_t)hi[3];
    return r;
}

// ---------------------------------------------------------------------------
// Vp layout (validated R14/R15): per (bh,a): 32 sb-blocks of 4KB:
//   byte = (bh*NA+a)*131072 + sb*4096 + dt*1024 + (q*16 + l)*16 + e*2
// holding V[d = dt*16+l][s = sb*32 + s5] with s5 = (e>>2)*16 + q*4 + (e&3).
// ---------------------------------------------------------------------------

// ---------------------------------------------------------------------------
// fp32 -> bf16 bulk conversion, up to 6 segments.
// ---------------------------------------------------------------------------
__global__ __launch_bounds__(256) void cvt6(
    const float* __restrict__ s0, bf16_t* __restrict__ d0, int c0,
    const float* __restrict__ s1, bf16_t* __restrict__ d1, int c1,
    const float* __restrict__ s2, bf16_t* __restrict__ d2, int c2,
    const float* __restrict__ s3, bf16_t* __restrict__ d3, int c3,
    const float* __restrict__ s4, bf16_t* __restrict__ d4, int c4,
    const float* __restrict__ s5, bf16_t* __restrict__ d5, int c5)
{
    const int bid = blockIdx.x;
    const float* s; bf16_t* d; int rel;
    if      (bid < c0) { s = s0; d = d0; rel = bid; }
    else if (bid < c1) { s = s1; d = d1; rel = bid - c0; }
    else if (bid < c2) { s = s2; d = d2; rel = bid - c1; }
    else if (bid < c3) { s = s3; d = d3; rel = bid - c2; }
    else if (bid < c4) { s = s4; d = d4; rel = bid - c3; }
    else               { s = s5; d = d5; rel = bid - c4; }
    const int t = threadIdx.x;
#pragma unroll
    for (int k = 0; k < 4; k++) {
        size_t u = (size_t)rel * 1024 + k * 256 + t;   // f32x4 unit index
        f32x4 v = reinterpret_cast<const f32x4*>(s)[u];
        bf16x4 o;
        o[0] = (bf16_t)v[0]; o[1] = (bf16_t)v[1];
        o[2] = (bf16_t)v[2]; o[3] = (bf16_t)v[3];
        reinterpret_cast<bf16x4*>(d)[u] = o;
    }
}

// ---------------------------------------------------------------------------
// R16 gemm8: 8-phase-style schedule for the merged QKV GEMM.
// Tile 256x128, BK=64, 8 waves (4M x 2N), per-wave 64x64 (4x4 MFMA frags).
// LDS: 3 buffers x 48KB (A 32K chunk-major | B 16K) = 144KB, 1 block/CU.
// Depth-2 staging: stage(it+2) issued during iter it (3 gl_lds16 per wave
// per phase); iteration-top s_waitcnt vmcnt(6) + raw s_barrier -- never
// drains in-loop (stage(it+1)'s 6 loads stay in flight across the barrier).
// Each iteration = 2 phases (ks=0,1): {8 ds_read frags || stage-half ->
// setprio(1) -> 16 MFMA -> setprio(0) -> barrier}. Phase-split creates the
// wave role diversity that makes setprio effective (T3+T4+T5); chunk-major
// LDS layout is measured conflict-free, so no swizzle needed.
// Buffer reuse safety: stage(it+3) (issued during it+1, into buf[it%3])
// is ordered after iter it's reads by the it+1 top barrier (all ds_reads
// retired via MFMA lgkmcnt deps before any wave passes it).
// Blocks [0,576): KV (emode 1). [576,672): Q (emode 0) via X2/W2/bias2.
// ---------------------------------------------------------------------------
__global__ __launch_bounds__(512) void gemm8(
    const bf16_t* __restrict__ X,
    const bf16_t* __restrict__ W0, const bf16_t* __restrict__ W1,
    const float* __restrict__ bias0, const float* __restrict__ bias1,
    bf16_t* __restrict__ outK, bf16_t* __restrict__ outV,
    const bf16_t* __restrict__ X2, const bf16_t* __restrict__ W2,
    const float* __restrict__ bias2, bf16_t* __restrict__ outQ)
{
    constexpr int BUFSZ = 49152;                  // A 32K + B 16K
    __shared__ __align__(16) char smem[3 * BUFSZ];

    const int t = threadIdx.x;
    const int lane = t & 63, w = t >> 6;          // w in [0,8)
    const int quad = lane >> 4, l15 = lane & 15;
    const int wm = w >> 1, wn = w & 1;            // 4M x 2N wave grid

    int emode = 1, nt = 12, bid = blockIdx.x;
    const bf16_t* Xp = X;
    const bf16_t* Wp = W0;
    const float*  b0 = bias0;
    if (bid >= 576) {                             // Q region
        emode = 0; nt = 6; bid -= 576;
        Xp = X2; Wp = W2; b0 = bias2;
    }

    // XCD-aware swizzle
    const int xcd = bid & 7, jj = bid >> 3;
    const int n_t = jj % nt, slab = jj / nt;
    const int m0 = (slab * 8 + xcd) * 256;
    const int n0 = n_t * 128;

    const bf16_t* Wsel = (emode == 1 && n0 >= 768) ? W1 : Wp;
    const int n0b = (emode == 1 && n0 >= 768) ? n0 - 768 : n0;

    // 6 staging instrs per wave; global instr idx g = w*6 + i, i in [0,6).
    // g < 32: A, ks = g>>4, mt = g&15, LDS off g*1024.
    // g >= 32: B, gb = g-32, ks = gb>>3, ntile = gb&7, LDS off g*1024.
    const bf16_t* sp[6];
    int loff[6];
#pragma unroll
    for (int i = 0; i < 6; i++) {
        int g = w * 6 + i;
        loff[i] = g * 1024;
        if (g < 32) {
            int ks = g >> 4, mt = g & 15;
            sp[i] = Xp + (size_t)(m0 + mt * 16 + l15) * NHID + ks * 32 + quad * 8;
        } else {
            int gb = g - 32;
            int ks = gb >> 3, ntile = gb & 7;
            sp[i] = Wsel + (size_t)(n0b + ntile * 16 + l15) * NHID + ks * 32 + quad * 8;
        }
    }

    auto stage_half = [&](char* base, int h) {     // 3 instrs per half
#pragma unroll
        for (int i = 0; i < 3; i++) {
            int idx = h * 3 + i;
            gl_lds16(sp[idx], base + loff[idx]);
            sp[idx] += 64;                         // BK=64 elements
        }
    };

    f32x4 acc[4][4];
#pragma unroll
    for (int i = 0; i < 4; i++)
#pragma unroll
        for (int j = 0; j < 4; j++) acc[i][j] = 0.0f;

    constexpr int KITER = NHID / 64;               // 12
    stage_half(smem, 0);          stage_half(smem, 1);           // stage(0)
    stage_half(smem + BUFSZ, 0);  stage_half(smem + BUFSZ, 1);   // stage(1)

    for (int it = 0; it < KITER; ++it) {
        if (it == KITER - 1) asm volatile("s_waitcnt vmcnt(0)" ::: "memory");
        else                 asm volatile("s_waitcnt vmcnt(6)" ::: "memory");
        __builtin_amdgcn_s_barrier();              // all waves' stage(it) done

        const char* rb = smem + (it % 3) * BUFSZ;
        char* pb = smem + ((it + 2) % 3) * BUFSZ;
        const bool dostage = (it + 2 < KITER);

#pragma unroll
        for (int ks = 0; ks < 2; ++ks) {           // 2 phases per iteration
            bf16x8 af[4], bfr[4];
#pragma unroll
            for (int i = 0; i < 4; i++)
                af[i] = *(const bf16x8*)(rb + (ks * 16 + wm * 4 + i) * 1024 + lane * 16);
#pragma unroll
            for (int j = 0; j < 4; j++)
                bfr[j] = *(const bf16x8*)(rb + 32768 + (ks * 8 + wn * 4 + j) * 1024 + lane * 16);
            if (dostage) stage_half(pb, ks);
            __builtin_amdgcn_s_setprio(1);
#pragma unroll
            for (int i = 0; i < 4; i++)
#pragma unroll
                for (int j = 0; j < 4; j++)
                    acc[i][j] = MFMA(af[i], bfr[j], acc[i][j]);
            __builtin_amdgcn_s_setprio(0);
            if (ks == 0) __builtin_amdgcn_s_barrier();   // phase boundary
        }
        // iter-top barrier of it+1 orders buffer reuse for stage(it+3)
    }

    // ---- epilogue: per-wave 64x64 at (m0 + wm*64, n0 + wn*64) ----
#pragma unroll
    for (int i = 0; i < 4; i++) {
#pragma unroll
        for (int j = 0; j < 4; j++) {
            const int n = n0 + wn * 64 + j * 16 + l15;
            float bn;
            if (emode == 1) bn = (n < 768) ? b0[n] : bias1[n - 768];
            else            bn = b0[n];
            if (emode == 1 && n >= 768) {
                // Vp layout, bf16x4-packed (rg -> consecutive e-slots)
                const int m = m0 + wm * 64 + i * 16 + quad * 4;
                int b = m / (NA * NS);
                int rem = m - b * (NA * NS);
                int a = rem >> 10, s = rem & 1023;
                int hh = (n - 768) >> 6;
                bf16x4 pk;
#pragma unroll
                for (int rg = 0; rg < 4; rg++) pk[rg] = (bf16_t)(acc[i][j][rg] + bn);
                char* dst = (char*)outV + (size_t)((b * NHEADS + hh) * NA + a) * 131072
                            + (size_t)(s >> 5) * 4096 + j * 1024
                            + (quad * 16 + l15) * 16 + (i & 1) * 8;
                *reinterpret_cast<bf16x4*>(dst) = pk;
            } else {
#pragma unroll
                for (int rg = 0; rg < 4; rg++) {
                    const int m = m0 + wm * 64 + i * 16 + quad * 4 + rg;
                    float v = acc[i][j][rg] + bn;
                    if (emode == 0) {
                        int b = m >> 10, s = m & 1023, hh = n >> 6, d = n & 63;
                        outQ[(((size_t)(b * NHEADS + hh) * NS) + s) * HD + d] = (bf16_t)v;
                    } else {
                        int b = m / (NA * NS);
                        int rem = m - b * (NA * NS);
                        int a = rem >> 10, s = rem & 1023;
                        int hh = n >> 6, d = n & 63;
                        outK[((((size_t)(b * NHEADS + hh) * NA + a) * NS) + s) * HD + d] = (bf16_t)v;
                    }
                }
            }
        }
    }
}

// ---------------------------------------------------------------------------
// Projection GEMM (R15 structure), used for O-proj and tiers 2/3.
// 128x128 tile, BK=32, 4 waves, 2 buffers + 2 raw barriers + counted vmcnt.
// ---------------------------------------------------------------------------
template <int MODE, int NT, bool ABF, bool BBF>
__global__ __launch_bounds__(256) void proj_gemm(
    const void* __restrict__ Xv,
    const void* __restrict__ W0v, const void* __restrict__ W1v,
    const float* __restrict__ bias0, const float* __restrict__ bias1,
    const float* __restrict__ resid,
    bf16_t* __restrict__ out0, bf16_t* __restrict__ out1,
    float* __restrict__ outf)
{
    constexpr int ASZ   = ABF ? 8192 : 16384;
    constexpr int BSZ   = BBF ? 8192 : 16384;
    constexpr int BUFSZ = ASZ + BSZ;
    constexpr int LPS   = (ABF ? 2 : 4) + (BBF ? 2 : 4);
    __shared__ __align__(16) char smem[2 * BUFSZ];

    const int t = threadIdx.x;
    const int lane = t & 63, w = t >> 6;
    const int quad = lane >> 4, l15 = lane & 15;
    const int wm = w >> 1, wn = w & 1;

    const int bid = blockIdx.x;
    const int xcd = bid & 7, jj = bid >> 3;
    const int n_t = jj % NT, slab = jj / NT;
    const int m0 = (slab * 8 + xcd) * 128;
    const int n0 = n_t * 128;

    const void* Wselv = (MODE == 1 && n0 >= 768) ? W1v : W0v;
    const int n0b = (MODE == 1 && n0 >= 768) ? n0 - 768 : n0;

    const int srow  = lane >> 3;
    const int schnk = (lane & 7) ^ srow;
    const float*  Apf[4];
    const bf16_t* Apb[2];
    const float*  Bpf[4];
    const bf16_t* Bpb[2];
    if constexpr (ABF) {
        const bf16_t* X = (const bf16_t*)Xv;
#pragma unroll
        for (int i = 0; i < 2; i++) {
            int g = w * 2 + i;
            Apb[i] = X + (size_t)(m0 + g * 16 + l15) * NHID + quad * 8;
        }
    } else {
        const float* X = (const float*)Xv;
#pragma unroll
        for (int i = 0; i < 4; i++) {
            int g = w * 4 + i;
            Apf[i] = X + (size_t)(m0 + g * 8 + srow) * NHID + schnk * 4;
        }
    }
    if constexpr (BBF) {
        const bf16_t* Wb = (const bf16_t*)Wselv;
#pragma unroll
        for (int i = 0; i < 2; i++) {
            int g = w * 2 + i;
            Bpb[i] = Wb + (size_t)(n0b + g * 16 + l15) * NHID + quad * 8;
        }
    } else {
        const float* Wf = (const float*)Wselv;
#pragma unroll
        for (int i = 0; i < 4; i++) {
            int g = w * 4 + i;
            Bpf[i] = Wf + (size_t)(n0b + g * 8 + srow) * NHID + schnk * 4;
        }
    }

    auto stage = [&](char* base) {
        char* Ab = base;
        char* Bb = base + ASZ;
        if constexpr (ABF) {
#pragma unroll
            for (int i = 0; i < 2; i++) { gl_lds16(Apb[i], Ab + (w * 2 + i) * 1024); Apb[i] += 32; }
        } else {
#pragma unroll
            for (int i = 0; i < 4; i++) { gl_lds16(Apf[i], Ab + (w * 4 + i) * 1024); Apf[i] += 32; }
        }
        if constexpr (BBF) {
#pragma unroll
            for (int i = 0; i < 2; i++) { gl_lds16(Bpb[i], Bb + (w * 2 + i) * 1024); Bpb[i] += 32; }
        } else {
#pragma unroll
            for (int i = 0; i < 4; i++) { gl_lds16(Bpf[i], Bb + (w * 4 + i) * 1024); Bpf[i] += 32; }
        }
    };

    auto wait_one = [&]() {
        if constexpr (LPS == 4)      asm volatile("s_waitcnt vmcnt(4)" ::: "memory");
        else if constexpr (LPS == 6) asm volatile("s_waitcnt vmcnt(6)" ::: "memory");
        else                         asm volatile("s_waitcnt vmcnt(8)" ::: "memory");
    };

    f32x4 acc[4][4];
#pragma unroll
    for (int i = 0; i < 4; i++)
#pragma unroll
        for (int j = 0; j < 4; j++) acc[i][j] = 0.0f;

    constexpr int KITER = NHID / 32;   // 24
    stage(smem);

    for (int it = 0; it < KITER; ++it) {
        if (it + 1 < KITER) {
            stage(smem + ((it + 1) & 1) * BUFSZ);
            wait_one();
        } else {
            asm volatile("s_waitcnt vmcnt(0)" ::: "memory");
        }
        __builtin_amdgcn_s_barrier();

        char* Ab = smem + (it & 1) * BUFSZ;
        char* Bb = Ab + ASZ;

        bf16x8 af[4], bfr[4];
        const int pl = (2 * quad) ^ (l15 & 7);
#pragma unroll
        for (int i = 0; i < 4; i++) {
            if constexpr (ABF) {
                int mt = wm * 4 + i;
                af[i] = *(const bf16x8*)(Ab + (mt * 64 + lane) * 16);
            } else {
                int R = (wm * 4 + i) * 16 + l15;
                f32x4 lo = *(const f32x4*)(Ab + R * 128 + pl * 16);
                f32x4 hi = *(const f32x4*)(Ab + R * 128 + (pl ^ 1) * 16);
                af[i] = cvt8(lo, hi);
            }
        }
#pragma unroll
        for (int j = 0; j < 4; j++) {
            if constexpr (BBF) {
                int ntj = wn * 4 + j;
                bfr[j] = *(const bf16x8*)(Bb + (ntj * 64 + lane) * 16);
            } else {
                int R = (wn * 4 + j) * 16 + l15;
                f32x4 lo = *(const f32x4*)(Bb + R * 128 + pl * 16);
                f32x4 hi = *(const f32x4*)(Bb + R * 128 + (pl ^ 1) * 16);
                bfr[j] = cvt8(lo, hi);
            }
        }
#pragma unroll
        for (int i = 0; i < 4; i++)
#pragma unroll
            for (int j = 0; j < 4; j++)
                acc[i][j] = MFMA(af[i], bfr[j], acc[i][j]);
        __builtin_amdgcn_s_barrier();
    }

#pragma unroll
    for (int i = 0; i < 4; i++) {
#pragma unroll
        for (int j = 0; j < 4; j++) {
            const int n = n0 + wn * 64 + j * 16 + l15;
            float bn;
            if (MODE == 1) bn = (n < 768) ? bias0[n] : bias1[n - 768];
            else           bn = bias0[n];
            if (MODE == 1 && n >= 768) {
                const int m = m0 + wm * 64 + i * 16 + quad * 4;
                int b = m / (NA * NS);
                int rem = m - b * (NA * NS);
                int a = rem >> 10, s = rem & 1023;
                int hh = (n - 768) >> 6;
                bf16x4 pk;
#pragma unroll
                for (int rg = 0; rg < 4; rg++) pk[rg] = (bf16_t)(acc[i][j][rg] + bn);
                char* dst = (char*)out1 + (size_t)((b * NHEADS + hh) * NA + a) * 131072
                            + (size_t)(s >> 5) * 4096 + j * 1024
                            + (quad * 16 + l15) * 16 + (i & 1) * 8;
                *reinterpret_cast<bf16x4*>(dst) = pk;
            } else {
#pragma unroll
                for (int rg = 0; rg < 4; rg++) {
                    const int m = m0 + wm * 64 + i * 16 + quad * 4 + rg;
                    float v = acc[i][j][rg] + bn;
                    if (MODE == 0) {
                        int b = m >> 10, s = m & 1023, hh = n >> 6, d = n & 63;
                        out0[(((size_t)(b * NHEADS + hh) * NS) + s) * HD + d] = (bf16_t)v;
                    } else if (MODE == 1) {
                        int b = m / (NA * NS);
                        int rem = m - b * (NA * NS);
                        int a = rem >> 10, s = rem & 1023;
                        int hh = n >> 6, d = n & 63;
                        out0[((((size_t)(b * NHEADS + hh) * NA + a) * NS) + s) * HD + d] = (bf16_t)v;
                    } else {
                        v += resid[(size_t)m * NHID + n];
                        outf[(size_t)m * NHID + n] = v;
                    }
                }
            }
        }
    }
}

// ---------------------------------------------------------------------------
// Attention (R15 structure, unchanged): swapped QK^T, in-register softmax,
// Vp-matched PV, counted-vmcnt 2-barrier loop. LDS 48KB => 3 blocks/CU.
// ---------------------------------------------------------------------------
__global__ __launch_bounds__(256, 3) void attn_kernel(
    const bf16_t* __restrict__ Q, const bf16_t* __restrict__ K,
    const bf16_t* __restrict__ VT, bf16_t* __restrict__ AT)
{
    __shared__ __align__(16) char kv[2 * 24576];        // 2 x (K 12K + V 12K)

    const int t    = threadIdx.x;
    const int w    = t >> 6, lane = t & 63;
    const int quad = lane >> 4, l15 = lane & 15;

    int bh, qt;
    if (gridDim.x == 768) {           // full launch: XCD-local bh
        int xcd = blockIdx.x & 7, j = blockIdx.x >> 3;
        bh = (j >> 4) * 8 + xcd;      // 6 slabs x 8 xcd = 48
        qt = ((j & 15) << 2) | w;     // wave-level q-tiling: 0..63
    } else {                          // per-batch fallback
        bh = blockIdx.x >> 4;
        qt = ((blockIdx.x & 15) << 2) | w;
    }
    const int b  = bh / NHEADS, h = bh - b * NHEADS;
    const int q0 = qt * 16;

    const bf16_t* Qb = Q + ((size_t)bh * NS + q0) * HD;
    bf16x8 qf0 = load8(Qb + l15 * HD + quad * 8);
    bf16x8 qf1 = load8(Qb + l15 * HD + quad * 8 + 32);

    const char* gp[6];
    int gdelta[6], loff[6];
#pragma unroll
    for (int i = 0; i < 6; i++) {
        int g = w * 6 + i;
        loff[i] = g >= 12 ? 12288 + (g - 12) * 1024 : g * 1024;
        if (g < 12) {   // K: a|j|dh
            int a = g >> 2, j = (g >> 1) & 1, dh = g & 1;
            gp[i] = (const char*)(K + ((size_t)(bh * NA + a) * NS + j * 16 + l15) * HD
                                  + dh * 32 + quad * 8);
            gdelta[i] = 32 * HD * 2;
        } else {        // Vp: a|dt -- contiguous 1KB per instr
            int gi = g - 12;
            int a = gi >> 2, dt = gi & 3;
            gp[i] = (const char*)VT + (size_t)(bh * NA + a) * 131072
                    + dt * 1024 + (size_t)lane * 16;
            gdelta[i] = 4096;
        }
    }

    auto stage = [&](int buf) {
#pragma unroll
        for (int i = 0; i < 6; i++) {
            gl_lds16(gp[i], kv + buf * 24576 + loff[i]);
            gp[i] += gdelta[i];
        }
    };

    f32x4 acc[4];
#pragma unroll
    for (int dt = 0; dt < 4; dt++) acc[dt] = 0.0f;

    const float KS = 0.18033688011112042f;  // (1/8) * log2(e)

    stage(0);

    for (int it = 0; it < 32; ++it) {
        if (it + 1 < 32) {
            stage((it + 1) & 1);
            asm volatile("s_waitcnt vmcnt(6)" ::: "memory");
        } else {
            asm volatile("s_waitcnt vmcnt(0)" ::: "memory");
        }
        __builtin_amdgcn_s_barrier();

        const char* base = kv + (it & 1) * 24576;
        f32x4 sc[3][2];
#pragma unroll
        for (int a = 0; a < 3; a++) {
#pragma unroll
            for (int j = 0; j < 2; j++) {
                bf16x8 klo = *(const bf16x8*)(base + ((a * 4 + j * 2 + 0) * 64 + lane) * 16);
                bf16x8 khi = *(const bf16x8*)(base + ((a * 4 + j * 2 + 1) * 64 + lane) * 16);
                f32x4 z = 0.0f;
                f32x4 c0 = MFMA(klo, qf0, z);
                sc[a][j] = MFMA(khi, qf1, c0);
            }
        }
        f32x4 plo[3], phi[3];
#pragma unroll
        for (int j = 0; j < 2; j++) {
#pragma unroll
            for (int rg = 0; rg < 4; rg++) {
                float x0 = sc[0][j][rg], x1 = sc[1][j][rg], x2 = sc[2][j][rg];
                float mx = fmaxf(x0, fmaxf(x1, x2));
                float e0 = __builtin_amdgcn_exp2f((x0 - mx) * KS);
                float e1 = __builtin_amdgcn_exp2f((x1 - mx) * KS);
                float e2 = __builtin_amdgcn_exp2f((x2 - mx) * KS);
                float inv = __builtin_amdgcn_rcpf(e0 + e1 + e2);
                if (j == 0) {
                    plo[0][rg] = e0 * inv; plo[1][rg] = e1 * inv; plo[2][rg] = e2 * inv;
                } else {
                    phi[0][rg] = e0 * inv; phi[1][rg] = e1 * inv; phi[2][rg] = e2 * inv;
                }
            }
        }
#pragma unroll
        for (int a = 0; a < 3; a++) {
            bf16x8 pf = cvt8(plo[a], phi[a]);
#pragma unroll
            for (int dt = 0; dt < 4; dt++) {
                bf16x8 vf = *(const bf16x8*)(base + 12288 + ((a * 4 + dt) * 64 + lane) * 16);
                acc[dt] = MFMA(pf, vf, acc[dt]);
            }
        }
        __builtin_amdgcn_s_barrier();
    }

    bf16_t* Ob = AT + (size_t)b * NS * NHID;
#pragma unroll
    for (int dt = 0; dt < 4; dt++) {
#pragma unroll
        for (int rg = 0; rg < 4; rg++) {
            int qq = q0 + quad * 4 + rg;
            Ob[(size_t)qq * NHID + h * HD + dt * 16 + l15] = (bf16_t)acc[dt][rg];
        }
    }
}

// ---------------------------------------------------------------------------
// LayerNorm over rows of X (fp32, [4096,768]), IN PLACE.
// ---------------------------------------------------------------------------
__global__ __launch_bounds__(256) void ln_kernel(
    float* __restrict__ X, const float* __restrict__ gamma,
    const float* __restrict__ beta)
{
    const int row = blockIdx.x;
    const int t = threadIdx.x;
    float* x = X + (size_t)row * NHID;
    float v0 = x[t], v1 = x[t + 256], v2 = x[t + 512];
    float s  = v0 + v1 + v2;
    float s2 = v0 * v0 + v1 * v1 + v2 * v2;
#pragma unroll
    for (int off = 32; off > 0; off >>= 1) {
        s  += __shfl_down(s, off);
        s2 += __shfl_down(s2, off);
    }
    __shared__ float red[8];
    const int w = t >> 6, lane = t & 63;
    if (lane == 0) { red[w] = s; red[4 + w] = s2; }
    __syncthreads();
    s  = red[0] + red[1] + red[2] + red[3];
    s2 = red[4] + red[5] + red[6] + red[7];
    float mu  = s * (1.0f / NHID);
    float var = s2 * (1.0f / NHID) - mu * mu;
    float rs  = rsqrtf(fmaxf(var, 0.0f) + 1e-5f);
    x[t]       = (v0 - mu) * rs * gamma[t]       + beta[t];
    x[t + 256] = (v1 - mu) * rs * gamma[t + 256] + beta[t + 256];
    x[t + 512] = (v2 - mu) * rs * gamma[t + 512] + beta[t + 512];
}

// avg_weights == 1/3 identically (softmax over adapter axis sums to 1).
__global__ __launch_bounds__(256) void fill_third(float* __restrict__ p)
{
    const int i = blockIdx.x * 256 + threadIdx.x;
    f32x4 v = { 1.0f / 3.0f, 1.0f / 3.0f, 1.0f / 3.0f, 1.0f / 3.0f };
    *reinterpret_cast<f32x4*>(p + (size_t)i * 4) = v;
}

// ---------------------------------------------------------------------------
// out0 [0,12.58MB) fp32: O-proj X -> LN in place. out1: bf16 scratch.
// ws tier 1 (>=67,633,152 B): K 18.87 | Vp 18.87 | adaptb 18.87 | Wqb/Wkb/
// Wvb/Wob 1.18 ea | queryb 6.29 MB. tier 2 (>=37,748,736): K | Vp only.
// ---------------------------------------------------------------------------
extern "C" void kernel_launch(void* const* d_in, const int* in_sizes, int n_in,
                              void* d_out, int out_size, void* d_ws, size_t ws_size,
                              hipStream_t stream)
{
    (void)in_sizes; (void)n_in; (void)out_size;
    const float* query = (const float*)d_in[0];
    const float* adapt = (const float*)d_in[1];
    const float* Wq    = (const float*)d_in[2];
    const float* bq    = (const float*)d_in[3];
    const float* Wk    = (const float*)d_in[4];
    const float* bk    = (const float*)d_in[5];
    const float* Wv    = (const float*)d_in[6];
    const float* bv    = (const float*)d_in[7];
    const float* Wo    = (const float*)d_in[8];
    const float* bo    = (const float*)d_in[9];
    const float* gamma = (const float*)d_in[10];
    const float* beta  = (const float*)d_in[11];

    float*  out0  = (float*)d_out;            // 3,145,728 fp32
    float*  out1f = out0 + 3145728;           // 4,194,304 fp32
    bf16_t* out1b = (bf16_t*)out1f;

    dim3 blk(256);

    if (ws_size >= (size_t)67633152) {
        // ---- tier 1: full bf16 pipeline; gemm8 QKV + 2ph O-proj ----
        bf16_t* Kw  = (bf16_t*)d_ws;
        bf16_t* VTw = (bf16_t*)((char*)d_ws + 18874368);
        bf16_t* Adb = (bf16_t*)((char*)d_ws + 37748736);   // adapt bf16
        bf16_t* Wqb = (bf16_t*)((char*)d_ws + 56623104);
        bf16_t* Wkb = (bf16_t*)((char*)d_ws + 57802752);
        bf16_t* Wvb = (bf16_t*)((char*)d_ws + 58982400);
        bf16_t* Wob = (bf16_t*)((char*)d_ws + 60162048);
        bf16_t* Qcb = (bf16_t*)((char*)d_ws + 61341696);   // query bf16
        bf16_t* Qw  = out1b;
        bf16_t* ATw = out1b + 3145728;
        // bulk fp32->bf16: adapt 2304 | query 768 | Wq/Wk/Wv/Wo 144 each
        cvt6<<<dim3(3648), blk, 0, stream>>>(
            adapt, Adb, 2304, query, Qcb, 3072,
            Wq, Wqb, 3216, Wk, Wkb, 3360, Wv, Wvb, 3504, Wo, Wob, 3648);
        // merged QKV: 576 KV blocks (256x128) + 96 Q blocks
        gemm8<<<dim3(672), dim3(512), 0, stream>>>(
            Adb, Wkb, Wvb, bk, bv, Kw, VTw, Qcb, Wqb, bq, Qw);
        attn_kernel<<<dim3(768), blk, 0, stream>>>(Qw, Kw, VTw, ATw);
        proj_gemm<3, 6, true, true><<<dim3(192), blk, 0, stream>>>(
            ATw, Wob, nullptr, bo, nullptr, query, nullptr, nullptr, out0);
    } else if (ws_size >= (size_t)37748736) {
        // ---- tier 2: bf16 B only (W's in out1 spare), fp32 A ----
        bf16_t* Kw  = (bf16_t*)d_ws;
        bf16_t* VTw = (bf16_t*)((char*)d_ws + 18874368);
        bf16_t* Qw  = out1b;
        bf16_t* ATw = out1b + 3145728;
        bf16_t* Wqb = out1b + 6291456;         // 4.19MB spare in out1
        bf16_t* Wkb = Wqb + 589824;
        bf16_t* Wvb = Wkb + 589824;
        cvt6<<<dim3(432), blk, 0, stream>>>(
            Wq, Wqb, 144, Wk, Wkb, 288, Wv, Wvb, 432,
            Wv, Wvb, 432, Wv, Wvb, 432, Wv, Wvb, 432);
        proj_gemm<0, 6, false, true><<<dim3(192), blk, 0, stream>>>(
            query, Wqb, nullptr, bq, nullptr, nullptr, Qw, nullptr, nullptr);
        proj_gemm<1, 12, false, true><<<dim3(1152), blk, 0, stream>>>(
            adapt, Wkb, Wvb, bk, bv, nullptr, Kw, VTw, nullptr);
        attn_kernel<<<dim3(768), blk, 0, stream>>>(Qw, Kw, VTw, ATw);
        proj_gemm<3, 6, true, false><<<dim3(192), blk, 0, stream>>>(
            ATw, Wo, nullptr, bo, nullptr, query, nullptr, nullptr, out0);
    } else {
        // per-batch, zero-workspace fallback (scratch inside out1)
        bf16_t* Qc  = out1b;                  //   786,432 bf16
        bf16_t* ATc = out1b + 786432;         //   786,432 bf16
        bf16_t* Kc  = out1b + 1572864;        // 2,359,296 bf16
        bf16_t* VTc = out1b + 3932160;        // 2,359,296 bf16
        for (int b = 0; b < NB; b++) {
            const float* qb = query + (size_t)b * NS * NHID;
            const float* ab = adapt + (size_t)b * NA * NS * NHID;
            proj_gemm<0, 6, false, false><<<dim3(48), blk, 0, stream>>>(
                qb, Wq, nullptr, bq, nullptr, nullptr, Qc, nullptr, nullptr);
            proj_gemm<1, 12, false, false><<<dim3(288), blk, 0, stream>>>(
                ab, Wk, Wv, bk, bv, nullptr, Kc, VTc, nullptr);
            attn_kernel<<<dim3(192), blk, 0, stream>>>(Qc, Kc, VTc, ATc);
            proj_gemm<3, 6, true, false><<<dim3(48), blk, 0, stream>>>(
                ATc, Wo, nullptr, bo, nullptr, qb, nullptr, nullptr,
                out0 + (size_t)b * NS * NHID);
        }
    }

    ln_kernel<<<dim3(4096), blk, 0, stream>>>(out0, gamma, beta);
    fill_third<<<dim3(4096), blk, 0, stream>>>(out1f);
}